// Round 7
// baseline (339.730 us; speedup 1.0000x reference)
//
#include <hip/hip_runtime.h>

#define NND 50000
#define NE  800000
#define CF  128
#define NGR 512
#define DCAP 64   // per-node CSR slot capacity (Poisson(16); max deg ~38 for this dataset)

typedef __bf16 bf16;
typedef __bf16 bf16x2 __attribute__((ext_vector_type(2)));
typedef __bf16 bf16x4 __attribute__((ext_vector_type(4)));
typedef __bf16 bf16x8 __attribute__((ext_vector_type(8)));
typedef float  f32x4  __attribute__((ext_vector_type(4)));

// XOR-swizzled LDS index for B^T[n][k] (n:0..127, k:0..255 concat [wl;wr]).
__device__ __forceinline__ int swz(int n, int k) {
  return n * 256 + (((k >> 3) ^ (n & 31)) << 3) + (k & 7);
}

// ---------------- zero cnt (200000B) + avgsum (262144B) : contiguous 462848B ----------------
__global__ __launch_bounds__(256) void zero_k(int4* __restrict__ p) {
  p[blockIdx.x * 256 + threadIdx.x] = int4{0, 0, 0, 0};   // 113 blocks x 256 = 28928 int4 = 462848B
}

// ---- fused {x->bf16, weights->bf16, graph boundaries} + {8-class dst-confined CSR fill} ----
// Blocks 0..6249: conv work. Blocks 6250..9377: fill work (class c = (b-6250)&7 is constant
// mod 8 -> all writers of a csr line stay on one XCD, killing cross-XCD write amplification;
// int4 dst/src reads cut the 8x re-read cost). Independent outputs -> safe to co-schedule;
// fill's latency-bound waves hide behind conv's BW-bound ones.
__global__ __launch_bounds__(256) void convfill_k(const float* __restrict__ x,
                                                  bf16* __restrict__ xb,
                                                  const float* __restrict__ w1l, const float* __restrict__ w1r,
                                                  const float* __restrict__ w2l, const float* __restrict__ w2r,
                                                  const float* __restrict__ w3l, const float* __restrict__ w3r,
                                                  bf16* __restrict__ wb,
                                                  const int* __restrict__ batch,
                                                  int* __restrict__ gs,
                                                  const int* __restrict__ src,
                                                  const int* __restrict__ dst,
                                                  int* __restrict__ cnt,
                                                  unsigned short* __restrict__ csr) {
  if (blockIdx.x < 6250) {
    int t = blockIdx.x * 256 + threadIdx.x;   // t < 1,600,000 = NND*CF/4
    {
      f32x4 v = ((const f32x4*)x)[t];
      bf16x4 o;
      o[0] = (bf16)v[0]; o[1] = (bf16)v[1]; o[2] = (bf16)v[2]; o[3] = (bf16)v[3];
      ((bf16x4*)xb)[t] = o;
    }
    if (t < 49152) {  // 6 matrices x 16384 elems, 2 per thread
      int m = t >> 13, w = t & 8191;
      const float* sp = (m == 0) ? w1l : (m == 1) ? w1r : (m == 2) ? w2l
                      : (m == 3) ? w2r : (m == 4) ? w3l : w3r;
      float2 v = *(const float2*)(sp + w * 2);
      bf16x2 o;
      o[0] = (bf16)v.x; o[1] = (bf16)v.y;
      ((bf16x2*)wb)[t] = o;
    }
    if (t < NND) {
      int b = batch[t];
      if (t == 0) {
        for (int g = 0; g <= b; g++) gs[g] = 0;
      } else {
        int pb = batch[t - 1];
        for (int g = pb + 1; g <= b; g++) gs[g] = t;
      }
      if (t == NND - 1) {
        for (int g = b + 1; g <= NGR; g++) gs[g] = NND;
      }
    }
  } else {
    int bb = blockIdx.x - 6250;               // 3128 fill blocks = 391 chunks x 8 classes
    int r  = bb & 7;
    int lo = r * 6250, hi = lo + 6250;
    int ebase = (bb >> 3) * 2048;
#pragma unroll
    for (int h = 0; h < 2; h++) {
      int e = ebase + h * 1024 + threadIdx.x * 4;
      if (e < NE) {                            // NE % 4 == 0 -> full int4 in bounds
        int4 d4 = *(const int4*)(dst + e);
        int4 s4 = *(const int4*)(src + e);
        int dd[4] = {d4.x, d4.y, d4.z, d4.w};
        int ss[4] = {s4.x, s4.y, s4.z, s4.w};
#pragma unroll
        for (int u = 0; u < 4; u++) {
          int d = dd[u];
          if (d >= lo && d < hi) {
            int p = atomicAdd(&cnt[d], 1);
            if (p < DCAP) csr[d * DCAP + p] = (unsigned short)ss[u];
          }
        }
      }
    }
  }
}

// ---------------- mean-aggregate: wave = 1 node; 16 lanes x 16B; up to 32 edges in flight ----
__global__ __launch_bounds__(256) void agg_k(const bf16* __restrict__ xin,
                                             const int* __restrict__ cnt,
                                             const unsigned short* __restrict__ csr,
                                             bf16* __restrict__ aggout) {
  int wid  = (blockIdx.x * 256 + threadIdx.x) >> 6;
  int lane = threadIdx.x & 63;
  if (wid >= NND) return;
  int sub = lane >> 4;        // edge slot 0..3
  int c8  = (lane & 15) * 8;  // feature group
  int deg = min(cnt[wid], DCAP);
  int ebase = wid * DCAP;
  float a[8] = {};
  {
    int s[8]; float m[8]; bf16x8 v[8];
#pragma unroll
    for (int u = 0; u < 4; u++) {
      int i = u * 4 + sub;
      s[u] = csr[ebase + ((i < deg) ? i : 0)];
      m[u] = (i < deg) ? 1.f : 0.f;
    }
#pragma unroll
    for (int u = 0; u < 4; u++) v[u] = *(const bf16x8*)(xin + s[u] * 128 + c8);
    if (deg > 16) {  // wave-uniform: issue batch B (edges 16..31) before consuming A
#pragma unroll
      for (int u = 4; u < 8; u++) {
        int i = u * 4 + sub;
        s[u] = csr[ebase + ((i < deg) ? i : 0)];
        m[u] = (i < deg) ? 1.f : 0.f;
      }
#pragma unroll
      for (int u = 4; u < 8; u++) v[u] = *(const bf16x8*)(xin + s[u] * 128 + c8);
    }
#pragma unroll
    for (int u = 0; u < 4; u++)
#pragma unroll
      for (int j = 0; j < 8; j++) a[j] += m[u] * (float)v[u][j];
    if (deg > 16) {
#pragma unroll
      for (int u = 4; u < 8; u++)
#pragma unroll
        for (int j = 0; j < 8; j++) a[j] += m[u] * (float)v[u][j];
    }
  }
  for (int e = 32; e < deg; e += 16) {  // rare tail (deg>32, ~0.02% of nodes)
    int s[4]; float m[4]; bf16x8 v[4];
#pragma unroll
    for (int u = 0; u < 4; u++) {
      int i = e + u * 4 + sub;
      s[u] = csr[ebase + ((i < deg) ? i : 0)];
      m[u] = (i < deg) ? 1.f : 0.f;
    }
#pragma unroll
    for (int u = 0; u < 4; u++) v[u] = *(const bf16x8*)(xin + s[u] * 128 + c8);
#pragma unroll
    for (int u = 0; u < 4; u++)
#pragma unroll
      for (int j = 0; j < 8; j++) a[j] += m[u] * (float)v[u][j];
  }
#pragma unroll
  for (int j = 0; j < 8; j++) {
    a[j] += __shfl_xor(a[j], 16);
    a[j] += __shfl_xor(a[j], 32);
  }
  if (sub == 0) {
    float inv = 1.0f / fmaxf((float)deg, 1.0f);
    bf16x8 o;
#pragma unroll
    for (int j = 0; j < 8; j++) o[j] = (bf16)(a[j] * inv);
    *(bf16x8*)(aggout + wid * 128 + c8) = o;
  }
}

// ------- fused [agg|prev] @ [wl;wr] + b, ReLU, (+prev), LayerNorm, (+graph-pool partials) ----
// Block = 256 thr (4 waves); block covers 128 rows. When dopool!=0 (layer 3), the dead B-tile
// LDS is reused as a per-graph f32 accumulator (sorted batch -> block spans few graphs);
// one contiguous global atomicAdd stream per block merges into avgsum.
template <typename TO>
__global__ __launch_bounds__(256, 2) void gemm_k(
    const bf16* __restrict__ aggp, const bf16* __restrict__ prev,
    const bf16* __restrict__ wl, const bf16* __restrict__ wr,
    const float* __restrict__ bias, const float* __restrict__ gamma,
    const float* __restrict__ beta, TO* __restrict__ outp, int addres,
    const int* __restrict__ batchp, float* __restrict__ avgsum, int dopool) {
  __shared__ bf16 bt[128 * 256];
  int tid = threadIdx.x;
  for (int e = tid; e < 128 * 64; e += 256) {
    int k  = e >> 6;
    int n2 = (e & 63) << 1;
    {
      bf16x2 v = *(const bf16x2*)(wl + k * 128 + n2);
      bt[swz(n2, k)]     = v[0];
      bt[swz(n2 + 1, k)] = v[1];
    }
    {
      bf16x2 v = *(const bf16x2*)(wr + k * 128 + n2);
      bt[swz(n2, k + 128)]     = v[0];
      bt[swz(n2 + 1, k + 128)] = v[1];
    }
  }
  __syncthreads();

  int wave = tid >> 6, lane = tid & 63;
  int q = lane >> 4, r = lane & 15;
  int wrow = blockIdx.x * 128 + wave * 32;

  int arow[2];
#pragma unroll
  for (int rt = 0; rt < 2; rt++) {
    int ar = wrow + rt * 16 + r;
    arow[rt] = (ar < NND) ? ar : (NND - 1);  // clamped; OOB rows never stored
  }

  f32x4 acc[2][8] = {};

#pragma unroll
  for (int kk = 0; kk < 8; kk++) {
    int kof = kk * 32 + q * 8;
    bf16x8 af[2];
#pragma unroll
    for (int rt = 0; rt < 2; rt++) {
      const bf16* ap = (kk < 4) ? (aggp + arow[rt] * 128 + kof)
                                : (prev + arow[rt] * 128 + (kof - 128));
      af[rt] = *(const bf16x8*)ap;
    }
#pragma unroll
    for (int t = 0; t < 8; t++) {
      int n = t * 16 + r;
      bf16x8 bfrag = *(const bf16x8*)&bt[n * 256 + (((kof >> 3) ^ (n & 31)) << 3)];
#pragma unroll
      for (int rt = 0; rt < 2; rt++)
        acc[rt][t] = __builtin_amdgcn_mfma_f32_16x16x32_bf16(af[rt], bfrag, acc[rt][t], 0, 0, 0);
    }
  }

  // pool scratch setup (bt is dead after the MFMA loop)
  float* poolbuf = (float*)bt;
  int gmin = 0, gspan = 0;
  if (dopool) {
    __syncthreads();                        // all waves done reading bt
    int row0 = blockIdx.x * 128;            // always < NND (391 blocks)
    gmin  = batchp[row0];
    int gmax = batchp[min(row0 + 127, NND - 1)];
    gspan = gmax - gmin + 1;                // <= 128 -> fits the 64KB scratch exactly
    for (int i = tid; i < gspan * 128; i += 256) poolbuf[i] = 0.f;
    __syncthreads();
  }

  float biasf[8], gf[8], bef[8];
#pragma unroll
  for (int t = 0; t < 8; t++) {
    int c = t * 16 + r;
    biasf[t] = bias[c];
    gf[t]    = gamma[c];
    bef[t]   = beta[c];
  }

#pragma unroll
  for (int rt = 0; rt < 2; rt++) {
#pragma unroll
    for (int reg = 0; reg < 4; reg++) {
      int row = wrow + rt * 16 + q * 4 + reg;
      int rr  = (row < NND) ? row : (NND - 1);
      const bf16* prow = prev + rr * 128;
      float vals[8];
      float s = 0.f, s2 = 0.f;
#pragma unroll
      for (int t = 0; t < 8; t++) {
        float v = acc[rt][t][reg] + biasf[t];
        v = fmaxf(v, 0.f);
        if (addres) v += (float)prow[t * 16 + r];
        vals[t] = v;
        s += v;
        s2 += v * v;
      }
#pragma unroll
      for (int m = 1; m < 16; m <<= 1) {
        s  += __shfl_xor(s, m);
        s2 += __shfl_xor(s2, m);
      }
      float mean = s * (1.f / 128.f);
      float var  = fmaxf(s2 * (1.f / 128.f) - mean * mean, 0.f);
      float rstd = rsqrtf(var + 1e-5f);
      if (row < NND) {
        TO* orow = outp + row * 128;
        int gb = dopool ? batchp[row] : 0;
#pragma unroll
        for (int t = 0; t < 8; t++) {
          float o = (vals[t] - mean) * rstd * gf[t] + bef[t];
          orow[t * 16 + r] = (TO)o;
          if (dopool) atomicAdd(&poolbuf[(gb - gmin) * 128 + t * 16 + r], o);
        }
      }
    }
  }

  if (dopool) {
    __syncthreads();
    for (int i = tid; i < gspan * 128; i += 256)
      atomicAdd(&avgsum[gmin * 128 + i], poolbuf[i]);
  }
}

// ---------------- finalize: mean + 128x2 head per graph ----------------
__global__ __launch_bounds__(128) void poolfin_k(
    const float* __restrict__ avgsum, const int* __restrict__ gs,
    const float* __restrict__ wc, const float* __restrict__ bc,
    float* __restrict__ outv, float* __restrict__ avgv) {
  int g = blockIdx.x;
  int tid = threadIdx.x;           // 128 threads = 2 waves
  float s = avgsum[g * 128 + tid];
  int c = gs[g + 1] - gs[g];
  float avg = s / fmaxf((float)c, 1.f);
  avgv[g * 128 + tid] = avg;
  float p0 = avg * wc[tid * 2 + 0];
  float p1 = avg * wc[tid * 2 + 1];
#pragma unroll
  for (int m = 1; m < 64; m <<= 1) {
    p0 += __shfl_xor(p0, m);
    p1 += __shfl_xor(p1, m);
  }
  __shared__ float sp[4];
  if ((tid & 63) == 0) {
    sp[(tid >> 6) * 2]     = p0;
    sp[(tid >> 6) * 2 + 1] = p1;
  }
  __syncthreads();
  if (tid == 0) {
    outv[g * 2 + 0] = sp[0] + sp[2] + bc[0];
    outv[g * 2 + 1] = sp[1] + sp[3] + bc[1];
  }
}

extern "C" void kernel_launch(void* const* d_in, const int* in_sizes, int n_in,
                              void* d_out, int out_size, void* d_ws, size_t ws_size,
                              hipStream_t stream) {
  const float* x   = (const float*)d_in[0];
  const int* ei    = (const int*)d_in[1];
  const int* batch = (const int*)d_in[2];
  const float* w1l = (const float*)d_in[3],  *w1r = (const float*)d_in[4];
  const float* b1  = (const float*)d_in[5],  *g1  = (const float*)d_in[6],  *be1 = (const float*)d_in[7];
  const float* w2l = (const float*)d_in[8],  *w2r = (const float*)d_in[9];
  const float* b2  = (const float*)d_in[10], *g2  = (const float*)d_in[11], *be2 = (const float*)d_in[12];
  const float* w3l = (const float*)d_in[13], *w3r = (const float*)d_in[14];
  const float* b3  = (const float*)d_in[15], *g3  = (const float*)d_in[16], *be3 = (const float*)d_in[17];
  const float* wc  = (const float*)d_in[18], *bc  = (const float*)d_in[19];
  const int* srcv = ei;
  const int* dstv = ei + NE;

  char* base = (char*)d_ws;
  int*            cnt    = (int*)(base + 0);         // 200000 (zeroed by zero_k)
  float*          avgsum = (float*)(base + 200704);  // 262144 (zeroed by zero_k)
  int*            gs     = (int*)(base + 462848);    // 2052
  bf16*           wb     = (bf16*)(base + 465408);   // 196608 (6 x 128x128 bf16)
  unsigned short* csr    = (unsigned short*)(base + 662016);   // 6.4 MB
  bf16*           agg    = (bf16*)(base + 7062016);  // 12.8 MB
  bf16*           h1     = (bf16*)(base + 19862016); // 12.8 MB
  bf16*           h2xb   = (bf16*)(base + 32662016); // 12.8 MB: xb until gemm1, then h2

  bf16* wb1l = wb,          *wb1r = wb + 16384;
  bf16* wb2l = wb + 32768,  *wb2r = wb + 49152;
  bf16* wb3l = wb + 65536,  *wb3r = wb + 81920;

  float* outv = (float*)d_out;             // 1024
  float* h3   = outv + 1024;               // 50000*128
  float* avgv = outv + 1024 + NND * CF;    // 512*128

  zero_k<<<113, 256, 0, stream>>>((int4*)base);
  convfill_k<<<9378, 256, 0, stream>>>(x, h2xb, w1l, w1r, w2l, w2r, w3l, w3r, wb,
                                       batch, gs, srcv, dstv, cnt, csr);

  // layer 1 (xb aliases h2xb; dead after gemm1 consumes it)
  agg_k<<<12500, 256, 0, stream>>>(h2xb, cnt, csr, agg);
  gemm_k<bf16><<<391, 256, 0, stream>>>(agg, h2xb, wb1l, wb1r, b1, g1, be1, h1, 0,
                                        nullptr, nullptr, 0);
  // layer 2
  agg_k<<<12500, 256, 0, stream>>>(h1, cnt, csr, agg);
  gemm_k<bf16><<<391, 256, 0, stream>>>(agg, h1, wb2l, wb2r, b2, g2, be2, h2xb, 1,
                                        nullptr, nullptr, 0);
  // layer 3 (+ pool partials)
  agg_k<<<12500, 256, 0, stream>>>(h2xb, cnt, csr, agg);
  gemm_k<float><<<391, 256, 0, stream>>>(agg, h2xb, wb3l, wb3r, b3, g3, be3, h3, 1,
                                         batch, avgsum, 1);
  // finalize: mean + head
  poolfin_k<<<NGR, 128, 0, stream>>>(avgsum, gs, wc, bc, outv, avgv);
}

// Round 8
// 290.939 us; speedup vs baseline: 1.1677x; 1.1677x over previous
//
#include <hip/hip_runtime.h>

#define NND 50000
#define NE  800000
#define CF  128
#define NGR 512
#define DCAP 64   // per-node CSR slot capacity (Poisson(16); max deg ~38 for this dataset)

typedef __bf16 bf16;
typedef __bf16 bf16x2 __attribute__((ext_vector_type(2)));
typedef __bf16 bf16x4 __attribute__((ext_vector_type(4)));
typedef __bf16 bf16x8 __attribute__((ext_vector_type(8)));
typedef float  f32x4  __attribute__((ext_vector_type(4)));

// ---------------- zero cnt: 12544 int4 = 200704B >= 200000B ----------------
__global__ __launch_bounds__(256) void zero_k(int4* __restrict__ p) {
  p[blockIdx.x * 256 + threadIdx.x] = int4{0, 0, 0, 0};   // 49 blocks x 256
}

// ---- fused {x->bf16, weights->bf16 TRANSPOSED+SWIZZLED, graph boundaries} + {CSR fill} ----
// Weight layout written here IS the final LDS byte layout of gemm_k's B^T tile:
// per matrix m: elem (k,n) -> m*16384 + n*128 + (((k>>3)^(n&15))<<3) + (k&7).
// gemm staging then becomes a linear 16B memcpy (no per-block transpose work).
// Blocks 0..6249: conv work. Blocks 6250..9377: 8-class dst-confined CSR fill.
__global__ __launch_bounds__(256) void convfill_k(const float* __restrict__ x,
                                                  bf16* __restrict__ xb,
                                                  const float* __restrict__ w1l, const float* __restrict__ w1r,
                                                  const float* __restrict__ w2l, const float* __restrict__ w2r,
                                                  const float* __restrict__ w3l, const float* __restrict__ w3r,
                                                  bf16* __restrict__ wb,
                                                  const int* __restrict__ batch,
                                                  int* __restrict__ gs,
                                                  const int* __restrict__ src,
                                                  const int* __restrict__ dst,
                                                  int* __restrict__ cnt,
                                                  unsigned short* __restrict__ csr) {
  if (blockIdx.x < 6250) {
    int t = blockIdx.x * 256 + threadIdx.x;   // t < 1,600,000 = NND*CF/4
    {
      f32x4 v = ((const f32x4*)x)[t];
      bf16x4 o;
      o[0] = (bf16)v[0]; o[1] = (bf16)v[1]; o[2] = (bf16)v[2]; o[3] = (bf16)v[3];
      ((bf16x4*)xb)[t] = o;
    }
    if (t < 49152) {  // 6 matrices x 16384 elems, 2 per thread
      int m = t >> 13, w2 = t & 8191;
      const float* sp = (m == 0) ? w1l : (m == 1) ? w1r : (m == 2) ? w2l
                      : (m == 3) ? w2r : (m == 4) ? w3l : w3r;
      int e0 = w2 * 2;
      int k = e0 >> 7, n = e0 & 127;          // source w[k][n], n even
      float2 v = *(const float2*)(sp + e0);
      bf16* wm = wb + m * 16384;
      wm[n * 128       + ((((k >> 3) ^ (n       & 15)) << 3)) + (k & 7)] = (bf16)v.x;
      wm[(n + 1) * 128 + ((((k >> 3) ^ ((n + 1) & 15)) << 3)) + (k & 7)] = (bf16)v.y;
    }
    if (t < NND) {
      int b = batch[t];
      if (t == 0) {
        for (int g = 0; g <= b; g++) gs[g] = 0;
      } else {
        int pb = batch[t - 1];
        for (int g = pb + 1; g <= b; g++) gs[g] = t;
      }
      if (t == NND - 1) {
        for (int g = b + 1; g <= NGR; g++) gs[g] = NND;
      }
    }
  } else {
    int bb = blockIdx.x - 6250;               // 3128 fill blocks = 391 chunks x 8 classes
    int r  = bb & 7;
    int lo = r * 6250, hi = lo + 6250;
    int ebase = (bb >> 3) * 2048;
#pragma unroll
    for (int h = 0; h < 2; h++) {
      int e = ebase + h * 1024 + threadIdx.x * 4;
      if (e < NE) {                            // NE % 4 == 0 -> full int4 in bounds
        int4 d4 = *(const int4*)(dst + e);
        int4 s4 = *(const int4*)(src + e);
        int dd[4] = {d4.x, d4.y, d4.z, d4.w};
        int ss[4] = {s4.x, s4.y, s4.z, s4.w};
#pragma unroll
        for (int u = 0; u < 4; u++) {
          int d = dd[u];
          if (d >= lo && d < hi) {
            int p = atomicAdd(&cnt[d], 1);
            if (p < DCAP) csr[d * DCAP + p] = (unsigned short)ss[u];
          }
        }
      }
    }
  }
}

// ---------------- mean-aggregate: wave = 1 node; 16 lanes x 16B; up to 32 edges in flight ----
__global__ __launch_bounds__(256) void agg_k(const bf16* __restrict__ xin,
                                             const int* __restrict__ cnt,
                                             const unsigned short* __restrict__ csr,
                                             bf16* __restrict__ aggout) {
  int wid  = (blockIdx.x * 256 + threadIdx.x) >> 6;
  int lane = threadIdx.x & 63;
  if (wid >= NND) return;
  int sub = lane >> 4;        // edge slot 0..3
  int c8  = (lane & 15) * 8;  // feature group
  int deg = min(cnt[wid], DCAP);
  int ebase = wid * DCAP;
  float a[8] = {};
  {
    int s[8]; float m[8]; bf16x8 v[8];
#pragma unroll
    for (int u = 0; u < 4; u++) {
      int i = u * 4 + sub;
      s[u] = csr[ebase + ((i < deg) ? i : 0)];
      m[u] = (i < deg) ? 1.f : 0.f;
    }
#pragma unroll
    for (int u = 0; u < 4; u++) v[u] = *(const bf16x8*)(xin + s[u] * 128 + c8);
    if (deg > 16) {  // wave-uniform: issue batch B (edges 16..31) before consuming A
#pragma unroll
      for (int u = 4; u < 8; u++) {
        int i = u * 4 + sub;
        s[u] = csr[ebase + ((i < deg) ? i : 0)];
        m[u] = (i < deg) ? 1.f : 0.f;
      }
#pragma unroll
      for (int u = 4; u < 8; u++) v[u] = *(const bf16x8*)(xin + s[u] * 128 + c8);
    }
#pragma unroll
    for (int u = 0; u < 4; u++)
#pragma unroll
      for (int j = 0; j < 8; j++) a[j] += m[u] * (float)v[u][j];
    if (deg > 16) {
#pragma unroll
      for (int u = 4; u < 8; u++)
#pragma unroll
        for (int j = 0; j < 8; j++) a[j] += m[u] * (float)v[u][j];
    }
  }
  for (int e = 32; e < deg; e += 16) {  // rare tail (deg>32, ~0.02% of nodes)
    int s[4]; float m[4]; bf16x8 v[4];
#pragma unroll
    for (int u = 0; u < 4; u++) {
      int i = e + u * 4 + sub;
      s[u] = csr[ebase + ((i < deg) ? i : 0)];
      m[u] = (i < deg) ? 1.f : 0.f;
    }
#pragma unroll
    for (int u = 0; u < 4; u++) v[u] = *(const bf16x8*)(xin + s[u] * 128 + c8);
#pragma unroll
    for (int u = 0; u < 4; u++)
#pragma unroll
      for (int j = 0; j < 8; j++) a[j] += m[u] * (float)v[u][j];
  }
#pragma unroll
  for (int j = 0; j < 8; j++) {
    a[j] += __shfl_xor(a[j], 16);
    a[j] += __shfl_xor(a[j], 32);
  }
  if (sub == 0) {
    float inv = 1.0f / fmaxf((float)deg, 1.0f);
    bf16x8 o;
#pragma unroll
    for (int j = 0; j < 8; j++) o[j] = (bf16)(a[j] * inv);
    *(bf16x8*)(aggout + wid * 128 + c8) = o;
  }
}

// ---------------- fused [agg|prev] @ [wl;wr] + b, ReLU, (+prev), LayerNorm ----------------
// Block = 256 thr (4 waves) x 64 rows; wave = 16 rows. Two K-phases over a 32KB LDS tile
// (phase 0: wl from agg, phase 1: wr from prev). Weights arrive PRE-SWIZZLED from global
// (written once by convfill_k), so staging is a pure linear 16B memcpy. All 8 A-fragments
// (both phases) prefetched before the first barrier -> 8 loads in flight per thread.
// Grid 782 blocks, 32KB LDS -> ~3 blocks/CU resident, ~12 waves/CU.
template <typename TO>
__global__ __launch_bounds__(256, 4) void gemm_k(
    const bf16* __restrict__ aggp, const bf16* __restrict__ prev,
    const bf16* __restrict__ wswz,   // 2 matrices (wl,wr), 16384 elems each, pre-swizzled
    const float* __restrict__ bias, const float* __restrict__ gamma,
    const float* __restrict__ beta, TO* __restrict__ outp, int addres) {
  __shared__ bf16 bt[16384];   // 32KB
  int tid = threadIdx.x;
  int lane = tid & 63;
  int wave = tid >> 6;
  int q = lane >> 4, r = lane & 15;
  int wrow = blockIdx.x * 64 + wave * 16;
  int arow = min(wrow + r, NND - 1);   // clamped; OOB rows never stored

  // stage phase-0 tile (wl), linear copy
  {
    const bf16x8* g = (const bf16x8*)wswz;
#pragma unroll
    for (int i = 0; i < 8; i++)
      ((bf16x8*)bt)[tid + i * 256] = g[tid + i * 256];
  }
  // prefetch ALL A-fragments (both phases) while staging settles
  bf16x8 af0[4], af1[4];
  {
    const bf16* a0 = aggp + arow * 128 + q * 8;
    const bf16* a1 = prev + arow * 128 + q * 8;
#pragma unroll
    for (int kk = 0; kk < 4; kk++) af0[kk] = *(const bf16x8*)(a0 + kk * 32);
#pragma unroll
    for (int kk = 0; kk < 4; kk++) af1[kk] = *(const bf16x8*)(a1 + kk * 32);
  }
  __syncthreads();

  f32x4 acc[8] = {};
#pragma unroll
  for (int kk = 0; kk < 4; kk++) {
#pragma unroll
    for (int t = 0; t < 8; t++) {
      int n = t * 16 + r;
      bf16x8 bfrag = *(const bf16x8*)&bt[n * 128 + (((kk * 4 + q) ^ (n & 15)) << 3)];
      acc[t] = __builtin_amdgcn_mfma_f32_16x16x32_bf16(af0[kk], bfrag, acc[t], 0, 0, 0);
    }
  }
  __syncthreads();   // phase-0 readers done
  // stage phase-1 tile (wr)
  {
    const bf16x8* g = (const bf16x8*)(wswz + 16384);
#pragma unroll
    for (int i = 0; i < 8; i++)
      ((bf16x8*)bt)[tid + i * 256] = g[tid + i * 256];
  }
  __syncthreads();
#pragma unroll
  for (int kk = 0; kk < 4; kk++) {
#pragma unroll
    for (int t = 0; t < 8; t++) {
      int n = t * 16 + r;
      bf16x8 bfrag = *(const bf16x8*)&bt[n * 128 + (((kk * 4 + q) ^ (n & 15)) << 3)];
      acc[t] = __builtin_amdgcn_mfma_f32_16x16x32_bf16(af1[kk], bfrag, acc[t], 0, 0, 0);
    }
  }

  float biasf[8], gf[8], bef[8];
#pragma unroll
  for (int t = 0; t < 8; t++) {
    int c = t * 16 + r;
    biasf[t] = bias[c];
    gf[t]    = gamma[c];
    bef[t]   = beta[c];
  }

#pragma unroll
  for (int reg = 0; reg < 4; reg++) {
    int row = wrow + q * 4 + reg;
    int rr  = (row < NND) ? row : (NND - 1);
    const bf16* prow = prev + rr * 128;
    float vals[8];
    float s = 0.f, s2 = 0.f;
#pragma unroll
    for (int t = 0; t < 8; t++) {
      float v = acc[t][reg] + biasf[t];
      v = fmaxf(v, 0.f);
      if (addres) v += (float)prow[t * 16 + r];
      vals[t] = v;
      s += v;
      s2 += v * v;
    }
#pragma unroll
    for (int m = 1; m < 16; m <<= 1) {
      s  += __shfl_xor(s, m);
      s2 += __shfl_xor(s2, m);
    }
    float mean = s * (1.f / 128.f);
    float var  = fmaxf(s2 * (1.f / 128.f) - mean * mean, 0.f);
    float rstd = rsqrtf(var + 1e-5f);
    if (row < NND) {
      TO* orow = outp + row * 128;
#pragma unroll
      for (int t = 0; t < 8; t++)
        orow[t * 16 + r] = (TO)((vals[t] - mean) * rstd * gf[t] + bef[t]);
    }
  }
}

// ---------------- fused mean-pool + head (sorted batch, no atomics) ----------------
__global__ __launch_bounds__(256) void poolhead_k(
    const float* __restrict__ h3, const int* __restrict__ gs,
    const float* __restrict__ wc, const float* __restrict__ bc,
    float* __restrict__ outv, float* __restrict__ avgv) {
  int g = blockIdx.x;
  int s = gs[g], epos = gs[g + 1];
  int tid = threadIdx.x;
  int wave = tid >> 6, lane = tid & 63;
  float a0 = 0.f, a1 = 0.f;
  for (int row = s + wave; row < epos; row += 4) {
    float2 v = *(const float2*)(h3 + row * 128 + 2 * lane);
    a0 += v.x; a1 += v.y;
  }
  __shared__ float red[4][128];
  red[wave][2 * lane]     = a0;
  red[wave][2 * lane + 1] = a1;
  __syncthreads();
  __shared__ float sp[4];
  if (tid < 128) {
    float t4  = red[0][tid] + red[1][tid] + red[2][tid] + red[3][tid];
    float inv = 1.f / fmaxf((float)(epos - s), 1.f);
    float avg = t4 * inv;
    avgv[g * 128 + tid] = avg;
    float p0 = avg * wc[tid * 2 + 0];
    float p1 = avg * wc[tid * 2 + 1];
#pragma unroll
    for (int m = 1; m < 64; m <<= 1) {
      p0 += __shfl_xor(p0, m);
      p1 += __shfl_xor(p1, m);
    }
    if ((tid & 63) == 0) {
      sp[(tid >> 6) * 2]     = p0;
      sp[(tid >> 6) * 2 + 1] = p1;
    }
  }
  __syncthreads();
  if (tid == 0) {
    outv[g * 2 + 0] = sp[0] + sp[2] + bc[0];
    outv[g * 2 + 1] = sp[1] + sp[3] + bc[1];
  }
}

extern "C" void kernel_launch(void* const* d_in, const int* in_sizes, int n_in,
                              void* d_out, int out_size, void* d_ws, size_t ws_size,
                              hipStream_t stream) {
  const float* x   = (const float*)d_in[0];
  const int* ei    = (const int*)d_in[1];
  const int* batch = (const int*)d_in[2];
  const float* w1l = (const float*)d_in[3],  *w1r = (const float*)d_in[4];
  const float* b1  = (const float*)d_in[5],  *g1  = (const float*)d_in[6],  *be1 = (const float*)d_in[7];
  const float* w2l = (const float*)d_in[8],  *w2r = (const float*)d_in[9];
  const float* b2  = (const float*)d_in[10], *g2  = (const float*)d_in[11], *be2 = (const float*)d_in[12];
  const float* w3l = (const float*)d_in[13], *w3r = (const float*)d_in[14];
  const float* b3  = (const float*)d_in[15], *g3  = (const float*)d_in[16], *be3 = (const float*)d_in[17];
  const float* wc  = (const float*)d_in[18], *bc  = (const float*)d_in[19];
  const int* srcv = ei;
  const int* dstv = ei + NE;

  char* base = (char*)d_ws;
  int*            cnt  = (int*)(base + 0);          // 200000 (zeroed by zero_k, pad to 200704)
  int*            gs   = (int*)(base + 200704);     // 2052
  bf16*           wb   = (bf16*)(base + 204800);    // 196608 (6 x 128x128 bf16, pre-swizzled B^T)
  unsigned short* csr  = (unsigned short*)(base + 401408);  // 6.4 MB (50000 x 64 u16 slots)
  bf16*           agg  = (bf16*)(base + 6801408);   // 12.8 MB
  bf16*           h1   = (bf16*)(base + 19601408);  // 12.8 MB
  bf16*           h2xb = (bf16*)(base + 32401408);  // 12.8 MB: xb until gemm1, then h2

  float* outv = (float*)d_out;             // 1024
  float* h3   = outv + 1024;               // 50000*128
  float* avgv = outv + 1024 + NND * CF;    // 512*128

  zero_k<<<49, 256, 0, stream>>>((int4*)base);
  convfill_k<<<9378, 256, 0, stream>>>(x, h2xb, w1l, w1r, w2l, w2r, w3l, w3r, wb,
                                       batch, gs, srcv, dstv, cnt, csr);

  // layer 1 (xb aliases h2xb; dead after gemm1 consumes it)
  agg_k<<<12500, 256, 0, stream>>>(h2xb, cnt, csr, agg);
  gemm_k<bf16><<<782, 256, 0, stream>>>(agg, h2xb, wb,           b1, g1, be1, h1, 0);
  // layer 2
  agg_k<<<12500, 256, 0, stream>>>(h1, cnt, csr, agg);
  gemm_k<bf16><<<782, 256, 0, stream>>>(agg, h1, wb + 2 * 16384, b2, g2, be2, h2xb, 1);
  // layer 3
  agg_k<<<12500, 256, 0, stream>>>(h2xb, cnt, csr, agg);
  gemm_k<float><<<782, 256, 0, stream>>>(agg, h2xb, wb + 4 * 16384, b3, g3, be3, h3, 1);
  // pool + head
  poolhead_k<<<NGR, 256, 0, stream>>>(h3, gs, wc, bc, outv, avgv);
}